// Round 6
// baseline (804.815 us; speedup 1.0000x reference)
//
#include <hip/hip_runtime.h>
#include <hip/hip_bf16.h>

#define FLAT   2048
#define EDG    131072
#define NEF    64
#define EPA    32
#define EPB    32

typedef short  frag8  __attribute__((ext_vector_type(8)));   // 8 bf16 = 4 VGPRs
typedef float  f32x16 __attribute__((ext_vector_type(16)));  // MFMA 32x32 acc

__device__ __forceinline__ float siluf(float x){ return x / (1.f + __expf(-x)); }

__device__ __forceinline__ uint4 pack8(const float v[8]){
    union { uint4 u; __hip_bfloat16 h[8]; } r;
    #pragma unroll
    for (int i=0;i<8;i++) r.h[i] = __float2bfloat16(v[i]);
    return r.u;
}

// ---------------- tiny helpers ----------------
__global__ void k_zeroi(int* __restrict__ p, int n){
    int i = blockIdx.x*256 + threadIdx.x;
    if (i < n) p[i] = 0;
}

// count-sort of edges by att_src (2048 segments)
__global__ void k_count(const int* __restrict__ att_src, int* __restrict__ counts){
    int e = blockIdx.x*256 + threadIdx.x;
    if (e < EDG) atomicAdd(&counts[att_src[e]], 1);
}

__global__ void k_scan(const int* __restrict__ counts, int* __restrict__ offsets,
                       int* __restrict__ cursor){
    __shared__ int part[256];
    int tid = threadIdx.x;
    int base = tid*8;
    int c[8]; int ls = 0;
    #pragma unroll
    for (int i=0;i<8;i++){ c[i] = counts[base+i]; ls += c[i]; }
    part[tid] = ls;
    __syncthreads();
    int pre = 0;
    for (int j=0;j<tid;j++) pre += part[j];
    int run = pre;
    #pragma unroll
    for (int i=0;i<8;i++){ offsets[base+i] = run; cursor[base+i] = run; run += c[i]; }
    if (tid == 255) offsets[2048] = run;
}

__global__ void k_scatter(const int* __restrict__ att_src, int* __restrict__ cursor,
                          int* __restrict__ perm){
    int e = blockIdx.x*256 + threadIdx.x;
    if (e < EDG){
        int p = atomicAdd(&cursor[att_src[e]], 1);
        perm[p] = e;
    }
}

// vw_W2 (128x1152 f32, k-major) -> W2B fragment-major bf16
__global__ void k_cvtW2(const float* __restrict__ W2, __hip_bfloat16* __restrict__ W2B){
    int t = blockIdx.x*256 + threadIdx.x;
    if (t >= 36*8*512) return;
    int j    = t & 7;
    int lane = (t>>3) & 63;
    int cl   = lane & 31, half = lane >> 5;
    int kk   = t >> 9;           // tile*8+ks
    int ks   = kk & 7, tile = kk >> 3;
    int k = ks*16 + half*8 + j;
    int n = tile*32 + cl;
    W2B[t] = __float2bfloat16(W2[(size_t)k*1152 + n]);
}

// gW1 (273x128) -> gW1B frag-major; vw_W1 (49x128) -> vwW1B frag-major
__global__ void k_cvtW1s(const float* __restrict__ gW1, const float* __restrict__ vwW1,
                         __hip_bfloat16* __restrict__ gW1B, __hip_bfloat16* __restrict__ vwW1B){
    int t = blockIdx.x*256 + threadIdx.x;
    if (t < 4*18*512){
        int j = t & 7;
        int lane = (t>>3) & 63;
        int cl = lane & 31, half = lane >> 5;
        int kk = t >> 9;                 // b*18+ks
        int ks = kk % 18, b = kk / 18;
        int k = ks*16 + half*8 + j;
        int c = b*32 + cl;
        gW1B[t] = __float2bfloat16(k < 273 ? gW1[(size_t)k*128 + c] : 0.f);
    } else if (t < 4*18*512 + 4*4*512){
        int t2 = t - 4*18*512;
        int j = t2 & 7;
        int lane = (t2>>3) & 63;
        int cl = lane & 31, half = lane >> 5;
        int kk = t2 >> 9;                // b*4+ks
        int ks = kk & 3, b = kk >> 2;
        int k = ks*16 + half*8 + j;
        int c = b*32 + cl;
        vwW1B[t2] = __float2bfloat16(k < 49 ? vwW1[(size_t)k*128 + c] : 0.f);
    }
}

// scales: (64x32)@(32x128) silu @(128x24) -> expand to 40
__global__ void k_scales(const float* __restrict__ e_feat,
                         const float* __restrict__ W1, const float* __restrict__ b1,
                         const float* __restrict__ W2, const float* __restrict__ b2,
                         float* __restrict__ sfull){
    int j = threadIdx.x;
    if (j >= NEF) return;
    float acc[24];
    #pragma unroll
    for (int c=0;c<24;c++) acc[c] = b2[c];
    for (int h=0; h<128; h++){
        float a = b1[h];
        #pragma unroll 8
        for (int k=0;k<32;k++) a += e_feat[j*32+k]*W1[k*128+h];
        float s = siluf(a);
        #pragma unroll 8
        for (int c=0;c<24;c++) acc[c] += s*W2[h*24+c];
    }
    for (int c=0;c<16;c++)  sfull[j*40+c] = acc[c];
    for (int c=16;c<40;c++) sfull[j*40+c] = acc[16 + (c-16)/3];
}

// ---------------- K1a: per-edge prep, MFMA, frag-major weights ----------------
__global__ __launch_bounds__(256) void k_edge_prep(
    const float* __restrict__ h_flat, const int* __restrict__ z,
    const int* __restrict__ att_src, const int* __restrict__ att_dst,
    const float* __restrict__ att_dist, const float* __restrict__ att_vec,
    const float* __restrict__ z_emb_W,
    const __hip_bfloat16* __restrict__ vwW1B, const float* __restrict__ vw_b1,
    const __hip_bfloat16* __restrict__ gW1B, const float* __restrict__ gb1,
    const float* __restrict__ gW2, const float* __restrict__ gb2,
    __hip_bfloat16* __restrict__ hid_ws, float4* __restrict__ meta_ws)
{
    __shared__ uint4 s_ginf[1152];
    __shared__ uint4 s_winf[256];
    __shared__ float s_rbf[EPA][16];
    __shared__ float s_sh1[EPA][3];
    __shared__ float s_d[EPA], s_env[EPA], s_self[EPA], s_gsum[EPA];
    __shared__ int   s_src[EPA], s_dst[EPA];

    const int tid = threadIdx.x;
    const int e0  = blockIdx.x * EPA;

    if (tid < EPA){
        int e  = e0 + tid;
        int sr = att_src[e], ds = att_dst[e];
        s_src[tid] = sr; s_dst[tid] = ds;
        float d = att_dist[e];
        s_d[tid] = d;
        float isf = (sr == ds) ? 1.f : 0.f;
        s_self[tid] = isf;
        float dc = fmaxf(d, 1e-8f);
        float ux = att_vec[e*3+0]/dc, uy = att_vec[e*3+1]/dc, uz = att_vec[e*3+2]/dc;
        float m = (isf > 0.f) ? 0.f : 1.7320508075688772f;
        s_sh1[tid][0] = m*uy; s_sh1[tid][1] = m*uz; s_sh1[tid][2] = m*ux;
        s_env[tid] = (d < 5.0f) ? 0.5f*(__cosf(0.6283185307179586f*d)+1.f) : 0.f;
        s_gsum[tid] = gb2[0];
    }
    __syncthreads();

    #pragma unroll
    for (int r=0;r<2;r++){
        int t = r*256 + tid; int e = t>>4, jj = t&15;
        float x = (s_d[e] - (float)jj*(1.f/3.f)) * 3.f;
        s_rbf[e][jj] = __expf(-0.5f*x*x);
    }
    __syncthreads();

    {
        int m = tid & 31, kc = tid >> 5;
        float v[8];
        if (kc < 4){
            const float* zr = z_emb_W + (size_t)z[s_dst[m]]*32 + kc*8;
            float4 a = *(const float4*)(zr);
            float4 b = *(const float4*)(zr+4);
            v[0]=a.x; v[1]=a.y; v[2]=a.z; v[3]=a.w;
            v[4]=b.x; v[5]=b.y; v[6]=b.z; v[7]=b.w;
        } else if (kc == 4){
            v[0] = s_self[m];
            #pragma unroll
            for (int j=0;j<7;j++) v[1+j] = s_rbf[m][j];
        } else if (kc == 5){
            #pragma unroll
            for (int j=0;j<8;j++) v[j] = s_rbf[m][7+j];
        } else if (kc == 6){
            v[0] = s_rbf[m][15];
            #pragma unroll
            for (int j=1;j<8;j++) v[j] = 0.f;
        } else {
            #pragma unroll
            for (int j=0;j<8;j++) v[j] = 0.f;
        }
        s_winf[kc*32 + m] = pack8(v);
    }
    for (int q = tid; q < 1152; q += 256){
        int m = q & 31, kc = q >> 5;
        float v[8];
        if (kc < 32){
            int node = (kc < 16) ? s_src[m] : s_dst[m];
            int koff = (kc & 15)*8;
            const float* hp = h_flat + (size_t)node*128 + koff;
            float4 a = *(const float4*)(hp);
            float4 b = *(const float4*)(hp+4);
            v[0]=a.x; v[1]=a.y; v[2]=a.z; v[3]=a.w;
            v[4]=b.x; v[5]=b.y; v[6]=b.z; v[7]=b.w;
        } else if (kc == 32){
            #pragma unroll
            for (int j=0;j<8;j++) v[j] = s_rbf[m][j];
        } else if (kc == 33){
            #pragma unroll
            for (int j=0;j<8;j++) v[j] = s_rbf[m][8+j];
        } else if (kc == 34){
            v[0] = s_self[m];
            #pragma unroll
            for (int j=1;j<8;j++) v[j] = 0.f;
        } else {
            #pragma unroll
            for (int j=0;j<8;j++) v[j] = 0.f;
        }
        s_ginf[kc*32 + m] = pack8(v);
    }
    __syncthreads();

    const int lane = tid & 63, cl = lane & 31, half = lane >> 5;
    const int wave = tid >> 6;
    const int c    = wave*32 + cl;

    // vw GEMM: K=64 -> hid (fragment-order store)
    {
        f32x16 acc;
        float bias = vw_b1[c];
        #pragma unroll
        for (int i=0;i<16;i++) acc[i] = bias;
        #pragma unroll
        for (int ks=0;ks<4;ks++){
            frag8 af = *((const frag8*)&s_winf[(ks*2+half)*32 + cl]);
            frag8 bf = *(const frag8*)(vwW1B + ((size_t)(wave*4+ks)*64 + lane)*8);
            acc = __builtin_amdgcn_mfma_f32_32x32x16_bf16(af, bf, acc, 0, 0, 0);
        }
        __hip_bfloat16* hb = hid_ws + (size_t)blockIdx.x*4096
                           + (c>>4)*512 + ((c>>3)&1)*256 + (c&7);
        #pragma unroll
        for (int r=0;r<16;r++){
            int e = 4*half + (r&3) + 8*(r>>2);
            hb[e*8] = __float2bfloat16(siluf(acc[r]));
        }
    }
    // gate GEMM: K=288 -> silu @ gW2 -> reduce
    {
        f32x16 acc;
        float bias = gb1[c];
        #pragma unroll
        for (int i=0;i<16;i++) acc[i] = bias;
        #pragma unroll
        for (int ks=0;ks<18;ks++){
            frag8 af = *((const frag8*)&s_ginf[(ks*2+half)*32 + cl]);
            frag8 bf = *(const frag8*)(gW1B + ((size_t)(wave*18+ks)*64 + lane)*8);
            acc = __builtin_amdgcn_mfma_f32_32x32x16_bf16(af, bf, acc, 0, 0, 0);
        }
        float w2 = gW2[c];
        #pragma unroll
        for (int r=0;r<16;r++){
            float p = siluf(acc[r]) * w2;
            p += __shfl_down(p, 16, 32);
            p += __shfl_down(p,  8, 32);
            p += __shfl_down(p,  4, 32);
            p += __shfl_down(p,  2, 32);
            p += __shfl_down(p,  1, 32);
            if (cl == 0){
                int e = 4*half + (r&3) + 8*(r>>2);
                atomicAdd(&s_gsum[e], p);
            }
        }
    }
    __syncthreads();

    if (tid < EPA){
        float gate  = 1.f/(1.f+__expf(-s_gsum[tid]));
        float coeff = s_env[tid]*gate;
        meta_ws[e0+tid] = make_float4(coeff, s_sh1[tid][0], s_sh1[tid][1], s_sh1[tid][2]);
    }
}

// ---------------- K1b: MFMA edge GEMM + register contraction -> ve store ----------------
__device__ __forceinline__ f32x16 mfma_tile(const __hip_bfloat16* __restrict__ W2B,
                                            int tileIdx, float bias,
                                            const frag8 af[8], int lane)
{
    f32x16 acc;
    #pragma unroll
    for (int i=0;i<16;i++) acc[i] = bias;
    const frag8* wb = (const frag8*)(W2B + ((size_t)tileIdx*8)*512 + lane*8);
    #pragma unroll
    for (int ks=0;ks<8;ks++){
        frag8 bf = wb[ks*64];
        acc = __builtin_amdgcn_mfma_f32_32x32x16_bf16(af[ks], bf, acc, 0, 0, 0);
    }
    return acc;
}

__global__ __launch_bounds__(256) void k_edge_gemm(
    const float* __restrict__ h_full, const int* __restrict__ att_dst,
    const __hip_bfloat16* __restrict__ hid_ws, const float4* __restrict__ meta_ws,
    const __hip_bfloat16* __restrict__ W2B, const float* __restrict__ b2,
    float* __restrict__ ve_ws)
{
    __shared__ float s_hf[EPB][81];
    __shared__ float s_sT[32*32];
    __shared__ float s_t1T[16*32];
    __shared__ float s_vT[48*32];
    __shared__ float s_ve[EPB][40];
    __shared__ float s_p[EPB][8];
    __shared__ float s_coef[EPB];
    __shared__ float s_sh1[EPB][3];

    const int tid = threadIdx.x;
    const int e0  = blockIdx.x * EPB;
    const int lane = tid & 63, cl = lane & 31, half = lane >> 5;
    const int wave = tid >> 6;

    frag8 af[8];
    #pragma unroll
    for (int ks=0;ks<8;ks++)
        af[ks] = *(const frag8*)(hid_ws + (size_t)blockIdx.x*4096 + ks*512 + half*256 + cl*8);

    float biasv[10];
    {
        if (wave < 2){
            #pragma unroll
            for (int i=0;i<8;i++) biasv[i] = b2[(8*wave+i)*32 + cl];
            biasv[8] = 0.f; biasv[9] = 0.f;
        } else if (wave == 2){
            #pragma unroll
            for (int i=0;i<8;i++) biasv[i] = b2[512 + i*32 + cl];
            biasv[8] = b2[1024 + cl]; biasv[9] = b2[1056 + cl];
        } else {
            #pragma unroll
            for (int i=0;i<8;i++) biasv[i] = b2[768 + i*32 + cl];
            biasv[8] = b2[1088 + cl]; biasv[9] = b2[1120 + cl];
        }
    }

    if (tid < EPB){
        float4 mm = meta_ws[e0+tid];
        s_coef[tid]   = mm.x;
        s_sh1[tid][0] = mm.y; s_sh1[tid][1] = mm.z; s_sh1[tid][2] = mm.w;
    }
    #pragma unroll
    for (int r=0;r<10;r++){
        int t = r*256+tid; int e = t/80, k = t%80;
        s_hf[e][k] = h_full[(size_t)att_dst[e0+e]*80 + k];
    }
    for (int t=tid; t<EPB*48; t+=256){
        int e = t/48, k = t%48;
        if (k < 40) s_ve[e][k] = 0.f; else s_p[e][k-40] = 0.f;
    }
    __syncthreads();

    #pragma unroll
    for (int r=0;r<4;r++){
        int t = r*256+tid; int u = t>>5, e = t&31;
        s_sT[u*32+e] = s_hf[e][u];
    }
    #pragma unroll
    for (int r=0;r<6;r++){
        int t = r*256+tid; int q = t>>5, e = t&31;
        s_vT[q*32+e] = s_hf[e][32+q];
    }
    #pragma unroll
    for (int r=0;r<2;r++){
        int t = r*256+tid; int u = t>>5, e = t&31;
        s_t1T[u*32+e] = s_hf[e][32+u*3+0]*s_sh1[e][0]
                      + s_hf[e][32+u*3+1]*s_sh1[e][1]
                      + s_hf[e][32+u*3+2]*s_sh1[e][2];
    }
    __syncthreads();

    const int eoff = 4*half;
    const float RSQ3 = 0.5773502691896258f;

    if (wave < 2){
        float racc[16];
        #pragma unroll
        for (int r=0;r<16;r++) racc[r] = 0.f;
        #pragma unroll 1
        for (int t = 0; t < 8; ++t){
            int gt = 8*wave + t;
            f32x16 acc = mfma_tile(W2B, gt, biasv[t], af, lane);
            int u = 2*gt + (cl>>4);
            const float* wb = &s_sT[u*32 + eoff];
            #pragma unroll
            for (int g=0; g<4; g++){
                float4 w4 = *(const float4*)(wb + 8*g);
                racc[4*g+0] += acc[4*g+0]*w4.x;
                racc[4*g+1] += acc[4*g+1]*w4.y;
                racc[4*g+2] += acc[4*g+2]*w4.z;
                racc[4*g+3] += acc[4*g+3]*w4.w;
            }
        }
        int v = cl & 15;
        #pragma unroll
        for (int r=0;r<16;r++){
            int e = eoff + (r&3) + 8*(r>>2);
            atomicAdd(&s_ve[e][v], racc[r]);
        }
    } else {
        if (wave == 2){
            float racc[16];
            #pragma unroll
            for (int r=0;r<16;r++) racc[r] = 0.f;
            #pragma unroll 1
            for (int t = 0; t < 8; ++t){
                f32x16 acc = mfma_tile(W2B, 16+t, biasv[t], af, lane);
                int u = 2*t + (cl>>4);
                const float* wb = &s_t1T[u*32 + eoff];
                #pragma unroll
                for (int g=0; g<4; g++){
                    float4 w4 = *(const float4*)(wb + 8*g);
                    racc[4*g+0] += acc[4*g+0]*w4.x;
                    racc[4*g+1] += acc[4*g+1]*w4.y;
                    racc[4*g+2] += acc[4*g+2]*w4.z;
                    racc[4*g+3] += acc[4*g+3]*w4.w;
                }
            }
            int v = cl & 15;
            #pragma unroll
            for (int r=0;r<16;r++){
                int e = eoff + (r&3) + 8*(r>>2);
                atomicAdd(&s_ve[e][v], racc[r]*RSQ3);
            }
        } else {
            float racc[16];
            #pragma unroll
            for (int r=0;r<16;r++) racc[r] = 0.f;
            #pragma unroll 1
            for (int t = 0; t < 8; ++t){
                f32x16 acc = mfma_tile(W2B, 24+t, biasv[t], af, lane);
                int u = 4*t + (cl>>3);
                const float* wb = &s_sT[u*32 + eoff];
                #pragma unroll
                for (int g=0; g<4; g++){
                    float4 w4 = *(const float4*)(wb + 8*g);
                    racc[4*g+0] += acc[4*g+0]*w4.x;
                    racc[4*g+1] += acc[4*g+1]*w4.y;
                    racc[4*g+2] += acc[4*g+2]*w4.z;
                    racc[4*g+3] += acc[4*g+3]*w4.w;
                }
            }
            int v = cl & 7;
            #pragma unroll
            for (int r=0;r<16;r++){
                int e = eoff + (r&3) + 8*(r>>2);
                atomicAdd(&s_p[e][v], racc[r]);
            }
        }
        // w101
        {
            float r3[16][3];
            #pragma unroll
            for (int r=0;r<16;r++){ r3[r][0]=0.f; r3[r][1]=0.f; r3[r][2]=0.f; }
            int tbase = (wave == 2) ? 0 : 2;
            #pragma unroll 1
            for (int t = tbase; t < tbase+2; ++t){
                f32x16 acc = mfma_tile(W2B, 32+t, biasv[8+(t-tbase)], af, lane);
                int u = 4*t + (cl>>3);
                #pragma unroll
                for (int i=0;i<3;i++){
                    const float* vb = &s_vT[(u*3+i)*32 + eoff];
                    #pragma unroll
                    for (int g=0; g<4; g++){
                        float4 w4 = *(const float4*)(vb + 8*g);
                        r3[4*g+0][i] += acc[4*g+0]*w4.x;
                        r3[4*g+1][i] += acc[4*g+1]*w4.y;
                        r3[4*g+2][i] += acc[4*g+2]*w4.z;
                        r3[4*g+3][i] += acc[4*g+3]*w4.w;
                    }
                }
            }
            int v = cl & 7;
            #pragma unroll
            for (int r=0;r<16;r++){
                int e = eoff + (r&3) + 8*(r>>2);
                atomicAdd(&s_ve[e][16+v*3+0], r3[r][0]);
                atomicAdd(&s_ve[e][16+v*3+1], r3[r][1]);
                atomicAdd(&s_ve[e][16+v*3+2], r3[r][2]);
            }
        }
    }
    __syncthreads();

    // coalesced store of v_e (RFAN * coeff folded) — NO global atomics
    const float RFAN = 0.14433756729740643f; // 1/sqrt(48)
    float* vp = ve_ws + (size_t)e0*40;
    #pragma unroll
    for (int r=0;r<5;r++){
        int t = r*256+tid; int e = t/40, s = t%40;
        float val;
        if (s < 16) val = s_ve[e][s];
        else {
            int v = (s-16)/3, i3 = (s-16)%3;
            val = s_p[e][v]*s_sh1[e][i3] + s_ve[e][s];
        }
        vp[t] = val * RFAN * s_coef[e];
    }
}

// ---------------- segment gather: oirr[n] = sum over edges with src==n ----------------
__global__ __launch_bounds__(256) void k_gather(
    const float* __restrict__ ve_ws, const int* __restrict__ perm,
    const int* __restrict__ offsets, float* __restrict__ oirr)
{
    __shared__ float red[6][40];
    const int n = blockIdx.x;
    const int tid = threadIdx.x;
    const int g = tid/40, s = tid%40;
    const int st = offsets[n], en = offsets[n+1];
    if (g < 6){
        float acc = 0.f;
        for (int i = st+g; i < en; i += 6){
            int e = perm[i];
            acc += ve_ws[(size_t)e*40 + s];
        }
        red[g][s] = acc;
    }
    __syncthreads();
    if (tid < 40){
        float a = red[0][tid]+red[1][tid]+red[2][tid]
                + red[3][tid]+red[4][tid]+red[5][tid];
        oirr[(size_t)n*40 + tid] = a;
    }
}

// ---------------- K2: per-node output MLP ----------------
__global__ __launch_bounds__(256) void k_out(
    const float* __restrict__ oirr, const float* __restrict__ sfull,
    const float* __restrict__ W1, const float* __restrict__ b1,
    const float* __restrict__ W2, const float* __restrict__ b2,
    const float* __restrict__ W3, const float* __restrict__ b3,
    float* __restrict__ out)
{
    __shared__ float s_irr[40];
    __shared__ float s_inv[64][24];
    __shared__ float s_x[64][128];

    const int tid = threadIdx.x;
    const int n   = blockIdx.x;
    if (tid < 40) s_irr[tid] = oirr[(size_t)n*40 + tid];
    __syncthreads();

    #pragma unroll
    for (int r=0;r<6;r++){
        int t = r*256+tid; int j = t/24, c = t%24;
        float v;
        if (c < 16) v = s_irr[c]*sfull[j*40+c];
        else {
            int base = 16 + (c-16)*3;
            float ss = 1e-12f;
            #pragma unroll
            for (int i=0;i<3;i++){ float x = s_irr[base+i]*sfull[j*40+base+i]; ss += x*x; }
            v = sqrtf(ss);
        }
        s_inv[j][c] = v;
    }
    __syncthreads();

    const int h4 = (tid & 31)*4, jg = tid >> 5;
    float acc[8][4];

    #pragma unroll
    for (int jj=0;jj<8;jj++)
        #pragma unroll
        for (int hh=0;hh<4;hh++) acc[jj][hh] = b1[h4+hh];
    #pragma unroll
    for (int k=0;k<24;k+=4){
        float4 w0 = *(const float4*)&W1[(k+0)*128+h4];
        float4 w1 = *(const float4*)&W1[(k+1)*128+h4];
        float4 w2 = *(const float4*)&W1[(k+2)*128+h4];
        float4 w3 = *(const float4*)&W1[(k+3)*128+h4];
        #pragma unroll
        for (int jj=0;jj<8;jj++){
            float4 xv = *(const float4*)&s_inv[jg*8+jj][k];
            acc[jj][0] += xv.x*w0.x + xv.y*w1.x + xv.z*w2.x + xv.w*w3.x;
            acc[jj][1] += xv.x*w0.y + xv.y*w1.y + xv.z*w2.y + xv.w*w3.y;
            acc[jj][2] += xv.x*w0.z + xv.y*w1.z + xv.z*w2.z + xv.w*w3.z;
            acc[jj][3] += xv.x*w0.w + xv.y*w1.w + xv.z*w2.w + xv.w*w3.w;
        }
    }
    #pragma unroll
    for (int jj=0;jj<8;jj++)
        *(float4*)&s_x[jg*8+jj][h4] = make_float4(siluf(acc[jj][0]), siluf(acc[jj][1]),
                                                  siluf(acc[jj][2]), siluf(acc[jj][3]));
    __syncthreads();

    #pragma unroll
    for (int jj=0;jj<8;jj++)
        #pragma unroll
        for (int hh=0;hh<4;hh++) acc[jj][hh] = b2[h4+hh];
    for (int k=0;k<128;k+=4){
        float4 w0 = *(const float4*)&W2[(k+0)*128+h4];
        float4 w1 = *(const float4*)&W2[(k+1)*128+h4];
        float4 w2 = *(const float4*)&W2[(k+2)*128+h4];
        float4 w3 = *(const float4*)&W2[(k+3)*128+h4];
        #pragma unroll
        for (int jj=0;jj<8;jj++){
            float4 xv = *(const float4*)&s_x[jg*8+jj][k];
            acc[jj][0] += xv.x*w0.x + xv.y*w1.x + xv.z*w2.x + xv.w*w3.x;
            acc[jj][1] += xv.x*w0.y + xv.y*w1.y + xv.z*w2.y + xv.w*w3.y;
            acc[jj][2] += xv.x*w0.z + xv.y*w1.z + xv.z*w2.z + xv.w*w3.z;
            acc[jj][3] += xv.x*w0.w + xv.y*w1.w + xv.z*w2.w + xv.w*w3.w;
        }
    }
    __syncthreads();
    #pragma unroll
    for (int jj=0;jj<8;jj++)
        *(float4*)&s_x[jg*8+jj][h4] = make_float4(siluf(acc[jj][0]), siluf(acc[jj][1]),
                                                  siluf(acc[jj][2]), siluf(acc[jj][3]));
    __syncthreads();

    #pragma unroll
    for (int jj=0;jj<8;jj++)
        #pragma unroll
        for (int hh=0;hh<4;hh++) acc[jj][hh] = b3[h4+hh];
    for (int k=0;k<128;k+=4){
        float4 w0 = *(const float4*)&W3[(k+0)*128+h4];
        float4 w1 = *(const float4*)&W3[(k+1)*128+h4];
        float4 w2 = *(const float4*)&W3[(k+2)*128+h4];
        float4 w3 = *(const float4*)&W3[(k+3)*128+h4];
        #pragma unroll
        for (int jj=0;jj<8;jj++){
            float4 xv = *(const float4*)&s_x[jg*8+jj][k];
            acc[jj][0] += xv.x*w0.x + xv.y*w1.x + xv.z*w2.x + xv.w*w3.x;
            acc[jj][1] += xv.x*w0.y + xv.y*w1.y + xv.z*w2.y + xv.w*w3.y;
            acc[jj][2] += xv.x*w0.z + xv.y*w1.z + xv.z*w2.z + xv.w*w3.z;
            acc[jj][3] += xv.x*w0.w + xv.y*w1.w + xv.z*w2.w + xv.w*w3.w;
        }
    }
    #pragma unroll
    for (int jj=0;jj<8;jj++){
        int j = jg*8+jj;
        *(float4*)&out[((size_t)n*64 + j)*128 + h4] =
            make_float4(acc[jj][0], acc[jj][1], acc[jj][2], acc[jj][3]);
    }
}

// ---------------- launch ----------------
extern "C" void kernel_launch(void* const* d_in, const int* in_sizes, int n_in,
                              void* d_out, int out_size, void* d_ws, size_t ws_size,
                              hipStream_t stream)
{
    const float* h        = (const float*)d_in[0];
    const float* h_full   = (const float*)d_in[1];
    const float* e_feat   = (const float*)d_in[2];
    const float* att_dist = (const float*)d_in[3];
    const float* att_vec  = (const float*)d_in[4];
    const int*   z        = (const int*)d_in[5];
    const int* att_src    = (const int*)d_in[7];
    const int* att_dst    = (const int*)d_in[8];
    const float* z_emb_W  = (const float*)d_in[9];
    const float* vw_W1    = (const float*)d_in[10];
    const float* vw_b1    = (const float*)d_in[11];
    const float* vw_W2    = (const float*)d_in[12];
    const float* vw_b2    = (const float*)d_in[13];
    const float* gW1      = (const float*)d_in[14];
    const float* gb1      = (const float*)d_in[15];
    const float* gW2      = (const float*)d_in[16];
    const float* gb2      = (const float*)d_in[17];
    const float* emW1     = (const float*)d_in[18];
    const float* emb1     = (const float*)d_in[19];
    const float* emW2     = (const float*)d_in[20];
    const float* emb2     = (const float*)d_in[21];
    const float* oW1      = (const float*)d_in[22];
    const float* ob1      = (const float*)d_in[23];
    const float* oW2      = (const float*)d_in[24];
    const float* ob2      = (const float*)d_in[25];
    const float* oW3      = (const float*)d_in[26];
    const float* ob3      = (const float*)d_in[27];
    float* out = (float*)d_out;

    char* ws = (char*)d_ws;
    __hip_bfloat16* hid_ws = (__hip_bfloat16*)ws;                        // 33,554,432 B
    float4* meta_ws = (float4*)(ws + (size_t)EDG*128*2);                 //  2,097,152 B
    float*  ve_ws   = (float*)(ws + (size_t)EDG*128*2 + (size_t)EDG*16); // 20,971,520 B
    float*  oirr    = ve_ws + (size_t)EDG*40;                            //    327,680 B
    float*  sfull   = oirr + (size_t)FLAT*40;                            //     10,240 B
    __hip_bfloat16* W2B   = (__hip_bfloat16*)(sfull + (size_t)NEF*40);   //    294,912 B
    __hip_bfloat16* gW1B  = W2B  + (size_t)36*8*512;                     //     73,728 B
    __hip_bfloat16* vwW1B = gW1B + (size_t)4*18*512;                     //     16,384 B
    int* counts  = (int*)(vwW1B + (size_t)4*4*512);                      //      8,192 B
    int* offsets = counts + FLAT;                                        //      8,196 B
    int* cursor  = offsets + (FLAT+1);                                   //      8,192 B
    int* perm    = cursor + FLAT;                                        //    524,288 B

    k_zeroi  <<<(FLAT + 255)/256, 256, 0, stream>>>(counts, FLAT);
    k_count  <<<EDG/256, 256, 0, stream>>>(att_src, counts);
    k_scan   <<<1, 256, 0, stream>>>(counts, offsets, cursor);
    k_scatter<<<EDG/256, 256, 0, stream>>>(att_src, cursor, perm);
    k_cvtW2  <<<(36*8*512 + 255)/256, 256, 0, stream>>>(vw_W2, W2B);
    k_cvtW1s <<<(4*18*512 + 4*4*512 + 255)/256, 256, 0, stream>>>(gW1, vw_W1, gW1B, vwW1B);
    k_scales <<<1, 64, 0, stream>>>(e_feat, emW1, emb1, emW2, emb2, sfull);
    k_edge_prep<<<EDG/EPA, 256, 0, stream>>>(h, z, att_src, att_dst, att_dist, att_vec,
        z_emb_W, vwW1B, vw_b1, gW1B, gb1, gW2, gb2, hid_ws, meta_ws);
    k_edge_gemm<<<EDG/EPB, 256, 0, stream>>>(h_full, att_dst, hid_ws, meta_ws,
        W2B, vw_b2, ve_ws);
    k_gather<<<FLAT, 256, 0, stream>>>(ve_ws, perm, offsets, oirr);
    k_out<<<FLAT, 256, 0, stream>>>(oirr, sfull, oW1, ob1, oW2, ob2, oW3, ob3, out);
}